// Round 4
// baseline (191.729 us; speedup 1.0000x reference)
//
#include <hip/hip_runtime.h>
#include <hip/hip_bf16.h>

#define N_NODES 50000
#define N_EDGES 800000
#define F 128
#define PAD_ROWS 64   // tail-tile slack for fused_gemm A-loads
#define SCAN_BLK 256
#define NPAIR (N_NODES / 2)                      // 25000 packed node-pairs
#define SCAN_NB ((NPAIR + SCAN_BLK - 1) / SCAN_BLK)   // 98
#define NB_E 128                                 // edge blocks for counting sort
#define E_PER (N_EDGES / NB_E)                   // 6250

typedef _Float16 half8 __attribute__((ext_vector_type(8)));
typedef float floatx4 __attribute__((ext_vector_type(4)));

__device__ inline float wave_sum(float v) {
    #pragma unroll
    for (int o = 32; o > 0; o >>= 1) v += __shfl_xor(v, o);
    return v;
}

// high 16 bits hold an fp16 payload
__device__ inline float hi16_of(unsigned u) {
    union { unsigned short s; _Float16 h; } c;
    c.s = (unsigned short)(u >> 16);
    return (float)c.h;
}

__device__ inline half8 cvt8(const float4* p) {
    float4 a = p[0], b = p[1];
    half8 h;
    h[0]=(_Float16)a.x; h[1]=(_Float16)a.y; h[2]=(_Float16)a.z; h[3]=(_Float16)a.w;
    h[4]=(_Float16)b.x; h[5]=(_Float16)b.y; h[6]=(_Float16)b.z; h[7]=(_Float16)b.w;
    return h;
}

// ---------------- k_prep: pure streaming fp32->fp16 conversion (NO atomics) ----------------
__global__ __launch_bounds__(256) void k_prep(const float* __restrict__ feat,
                                              const float* __restrict__ Wp,
                                              const float* __restrict__ Ws,
                                              _Float16* __restrict__ featH,
                                              _Float16* __restrict__ WpH,
                                              _Float16* __restrict__ WsH) {
    int i = blockIdx.x * 256 + threadIdx.x;
    if (i < N_NODES * F / 8) {
        ((half8*)featH)[i] = cvt8((const float4*)feat + (size_t)i * 2);
    }
    if (i < F * F / 8) {
        ((half8*)WpH)[i] = cvt8((const float4*)Wp + (size_t)i * 2);
        ((half8*)WsH)[i] = cvt8((const float4*)Ws + (size_t)i * 2);
    }
}

// ---------------- k_hist: per-block LDS histogram of dst + per-edge within-block rank ----------------
// 100 KB static LDS. Counts per block per node <= 6250 < 2^16, so packed-pair
// atomicAdd(1 << 16*(d&1)) never carries across halves. The atomic's return value IS
// the edge's within-block rank -> persist it so k_fill needs no LDS at all.
__global__ __launch_bounds__(1024) void k_hist(const int* __restrict__ dst,
                                               unsigned* __restrict__ histW,
                                               unsigned short* __restrict__ rank16,
                                               int* __restrict__ syncCnt) {
    __shared__ unsigned cnt[NPAIR];   // 100 KB
    int t = threadIdx.x;
    for (int i = t; i < NPAIR; i += 1024) cnt[i] = 0;
    if (blockIdx.x == 0 && t == 0) *syncCnt = 0;   // reset for k_scan (ordered by kernel boundary)
    __syncthreads();
    int base = blockIdx.x * E_PER;
    for (int i = t; i < E_PER; i += 1024) {
        int d = dst[base + i];
        int sh = (d & 1) * 16;
        unsigned old = atomicAdd(&cnt[d >> 1], 1u << sh);
        rank16[base + i] = (unsigned short)((old >> sh) & 0xFFFFu);
    }
    __syncthreads();
    unsigned* out = histW + (size_t)blockIdx.x * NPAIR;
    for (int i = t; i < NPAIR; i += 1024) out[i] = cnt[i];
}

// ---------------- k_scan: per-node prefix over NB_E hist rows -> base16 + offsets (fused spin-sync) ----------------
// 98 blocks x 256 threads (one thread per node PAIR): trivially co-resident, spin cannot deadlock.
__global__ __launch_bounds__(SCAN_BLK) void k_scan(const unsigned* __restrict__ histW,
                                                   unsigned* __restrict__ baseW,
                                                   int* __restrict__ blockSums,
                                                   int* __restrict__ offsets,
                                                   int* __restrict__ syncCnt) {
    __shared__ int s[SCAN_BLK];
    __shared__ int bs[SCAN_BLK];
    int t = threadIdx.x;
    int i = blockIdx.x * SCAN_BLK + t;   // pair index: nodes 2i, 2i+1

    // serial prefix over edge-blocks; separate lo/hi running sums (u16 halves)
    int dLo = 0, dHi = 0;
    if (i < NPAIR) {
        #pragma unroll 8
        for (int b = 0; b < NB_E; ++b) {
            unsigned w = histW[(size_t)b * NPAIR + i];
            baseW[(size_t)b * NPAIR + i] = (unsigned)dLo | ((unsigned)dHi << 16);
            dLo += (int)(w & 0xFFFFu);
            dHi += (int)(w >> 16);
        }
    }
    int dT = dLo + dHi;

    // in-block inclusive scan of pair totals
    s[t] = dT;
    __syncthreads();
    for (int o = 1; o < SCAN_BLK; o <<= 1) {
        int u = (t >= o) ? s[t - o] : 0;
        __syncthreads();
        s[t] += u;
        __syncthreads();
    }
    int incl = s[t];
    int total = s[SCAN_BLK - 1];

    // publish block total, device-scope counter barrier
    if (t == 0) {
        __hip_atomic_store(&blockSums[blockIdx.x], total, __ATOMIC_RELAXED, __HIP_MEMORY_SCOPE_AGENT);
        __hip_atomic_fetch_add(syncCnt, 1, __ATOMIC_RELEASE, __HIP_MEMORY_SCOPE_AGENT);
        while (__hip_atomic_load(syncCnt, __ATOMIC_ACQUIRE, __HIP_MEMORY_SCOPE_AGENT) < SCAN_NB) {
            __builtin_amdgcn_s_sleep(1);
        }
    }
    __syncthreads();

    // redundant top-level scan of the 98 block sums
    int v = (t < SCAN_NB) ? __hip_atomic_load(&blockSums[t], __ATOMIC_RELAXED, __HIP_MEMORY_SCOPE_AGENT) : 0;
    bs[t] = v;
    __syncthreads();
    for (int o = 1; o < SCAN_BLK; o <<= 1) {
        int u = (t >= o) ? bs[t - o] : 0;
        __syncthreads();
        bs[t] += u;
        __syncthreads();
    }
    int blockPrefix = (blockIdx.x == 0) ? 0 : bs[blockIdx.x - 1];
    if (i < NPAIR) {
        int excl = incl - dT + blockPrefix;
        offsets[2 * i]     = excl;
        offsets[2 * i + 1] = excl + dLo;
    }
    if (blockIdx.x == 0 && t == 0) offsets[N_NODES] = N_EDGES;
}

// ---------------- k_fill: pure streaming scatter (no LDS, full occupancy) ----------------
// pos = offsets[d] + base16[b][d] + rank16[e]; all per-edge inputs coalesced,
// two random 2-4 B loads per edge hidden by massive TLP (3125 blocks).
__global__ __launch_bounds__(256) void k_fill(const int* __restrict__ src,
                                              const int* __restrict__ dst,
                                              const float* __restrict__ efeat,
                                              const int* __restrict__ offsets,
                                              const unsigned short* __restrict__ base16,
                                              const unsigned short* __restrict__ rank16,
                                              unsigned* __restrict__ csr) {
    int e = blockIdx.x * 256 + threadIdx.x;
    if (e < N_EDGES) {
        int d = dst[e];
        int b = e / E_PER;
        union { _Float16 h; unsigned short s; } c;
        c.h = (_Float16)efeat[e];
        int pos = offsets[d] + (int)base16[(size_t)b * N_NODES + d] + (int)rank16[e];
        csr[pos] = (unsigned)src[e] | ((unsigned)c.s << 16);
    }
}

// ---------------- k_gather: one wave per node; single-sweep fast path for deg<=64 ----------------
__global__ __launch_bounds__(256) void k_gather(const int* __restrict__ offsets,
                                                const unsigned* __restrict__ csr,
                                                const _Float16* __restrict__ featH,
                                                float* __restrict__ msum,
                                                _Float16* __restrict__ aggH) {
    int wid  = (blockIdx.x * 256 + threadIdx.x) >> 6;   // node id
    int lane = threadIdx.x & 63;
    if (wid >= N_NODES) return;
    int beg = offsets[wid], end = offsets[wid + 1];
    int deg = end - beg;
    int grp = lane >> 4;        // 0..3
    int lig = lane & 15;        // lane in group

    float acc[8];
    #pragma unroll
    for (int k = 0; k < 8; ++k) acc[k] = 0.f;
    float msacc = 0.f;

    if (deg <= 64) {
        // FAST PATH (covers essentially all nodes; avg deg = 16):
        // one csr read, one exp per edge (owner lane), shfl both src and m.
        int j = beg + lane;
        bool live = j < end;
        unsigned u = live ? csr[j] : 0u;
        float w = live ? hi16_of(u) : 0.f;
        float ws = wave_sum(w);
        float inv = (deg > 0) ? (1.0f / ws) : 0.0f;
        float mv = live ? __expf(-w * inv) : 0.f;
        msacc = mv;

        for (int it = 0; it < deg; it += 8) {
            int idx1 = it + grp;
            int idx2 = it + 4 + grp;
            unsigned u1 = __shfl(u, idx1);
            unsigned u2 = __shfl(u, idx2);
            float m1 = __shfl(mv, idx1);
            float m2 = __shfl(mv, idx2);
            bool p1 = idx1 < deg, p2 = idx2 < deg;
            half8 v1, v2;
            if (p1) v1 = *(const half8*)(featH + (size_t)(u1 & 0xFFFFu) * F + lig * 8);
            if (p2) v2 = *(const half8*)(featH + (size_t)(u2 & 0xFFFFu) * F + lig * 8);
            if (p1) {
                #pragma unroll
                for (int k = 0; k < 8; ++k) acc[k] += m1 * (float)v1[k];
            }
            if (p2) {
                #pragma unroll
                for (int k = 0; k < 8; ++k) acc[k] += m2 * (float)v2[k];
            }
        }
    } else {
        // SLOW PATH: two-pass (wsum sweep then main), exp once per edge + shfl
        float wsum = 0.f;
        for (int c = beg; c < end; c += 64) {
            int j = c + lane;
            wsum += (j < end) ? hi16_of(csr[j]) : 0.f;
        }
        wsum = wave_sum(wsum);
        float inv = 1.0f / wsum;

        for (int c = beg; c < end; c += 64) {
            int j = c + lane;
            int cnt = end - c; if (cnt > 64) cnt = 64;
            bool live = j < end;
            unsigned u = live ? csr[j] : 0u;
            float mv = live ? __expf(-hi16_of(u) * inv) : 0.f;
            msacc += mv;
            for (int it = 0; it < cnt; it += 8) {
                int idx1 = it + grp;
                int idx2 = it + 4 + grp;
                unsigned u1 = __shfl(u, idx1);
                unsigned u2 = __shfl(u, idx2);
                float m1 = __shfl(mv, idx1);
                float m2 = __shfl(mv, idx2);
                bool p1 = idx1 < cnt, p2 = idx2 < cnt;
                half8 v1, v2;
                if (p1) v1 = *(const half8*)(featH + (size_t)(u1 & 0xFFFFu) * F + lig * 8);
                if (p2) v2 = *(const half8*)(featH + (size_t)(u2 & 0xFFFFu) * F + lig * 8);
                if (p1) {
                    #pragma unroll
                    for (int k = 0; k < 8; ++k) acc[k] += m1 * (float)v1[k];
                }
                if (p2) {
                    #pragma unroll
                    for (int k = 0; k < 8; ++k) acc[k] += m2 * (float)v2[k];
                }
            }
        }
    }

    #pragma unroll
    for (int k = 0; k < 8; ++k) {
        acc[k] += __shfl_xor(acc[k], 16);
        acc[k] += __shfl_xor(acc[k], 32);
    }
    msacc = wave_sum(msacc);

    if (grp == 0) {
        half8 o;
        #pragma unroll
        for (int k = 0; k < 8; ++k) o[k] = (_Float16)acc[k];
        ((half8*)(aggH + (size_t)wid * F))[lig] = o;
    }
    if (lane == 0) msum[wid] = msacc;
}

// ---------------- fused_gemm: dual MFMA GEMM, weights staged in LDS ----------------
__global__ __launch_bounds__(512, 4) void fused_gemm(const _Float16* __restrict__ featH,
                                                     const _Float16* __restrict__ aggH,
                                                     const _Float16* __restrict__ WpH,
                                                     const float* __restrict__ bp,
                                                     const _Float16* __restrict__ WsH,
                                                     const float* __restrict__ bs,
                                                     const float* __restrict__ msum,
                                                     const int* __restrict__ offsets,
                                                     float* __restrict__ out) {
    __shared__ half8 sBS[2048];   // 32 KB
    __shared__ half8 sBP[2048];   // 32 KB

    int t = threadIdx.x;
    for (int c = t; c < 2048; c += 512) {
        int o  = c >> 4;
        int k8 = c & 15;
        int lane = (o & 15) | ((k8 & 3) << 4);
        int slot = ((o >> 4) * 4 + (k8 >> 2)) * 64 + lane;
        sBS[slot] = ((const half8*)WsH)[c];
        sBP[slot] = ((const half8*)WpH)[c];
    }
    __syncthreads();

    int wv   = t >> 6;
    int lane = t & 63;
    int n0   = blockIdx.x * 128 + wv * 16;   // tail waves compute garbage on pad rows; stores guarded
    int lrow = lane & 15;
    int quad = lane >> 4;

    floatx4 accS[8], accP[8];
    #pragma unroll
    for (int c = 0; c < 8; ++c) {
        accS[c] = (floatx4){0.f, 0.f, 0.f, 0.f};
        accP[c] = (floatx4){0.f, 0.f, 0.f, 0.f};
    }

    const half8* fr = (const half8*)(featH + (size_t)(n0 + lrow) * F) + quad;
    const half8* ar = (const half8*)(aggH  + (size_t)(n0 + lrow) * F) + quad;

    #pragma unroll
    for (int kt = 0; kt < 4; ++kt) {
        half8 aF = fr[kt * 4];
        half8 aA = ar[kt * 4];
        #pragma unroll
        for (int ct = 0; ct < 8; ++ct) {
            half8 bS = sBS[(ct * 4 + kt) * 64 + lane];
            half8 bP = sBP[(ct * 4 + kt) * 64 + lane];
            accS[ct] = __builtin_amdgcn_mfma_f32_16x16x32_f16(aF, bS, accS[ct], 0, 0, 0);
            accP[ct] = __builtin_amdgcn_mfma_f32_16x16x32_f16(aA, bP, accP[ct], 0, 0, 0);
        }
    }

    float ms[4], inv[4];
    int gn[4];
    #pragma unroll
    for (int r = 0; r < 4; ++r) {
        int g = n0 + quad * 4 + r;
        gn[r] = g;
        bool ok = g < N_NODES;
        ms[r]  = ok ? msum[g] : 0.f;
        float dv = ok ? fmaxf((float)(offsets[g + 1] - offsets[g]), 1.0f) : 1.0f;
        inv[r] = 1.0f / dv;
    }
    #pragma unroll
    for (int ct = 0; ct < 8; ++ct) {
        int c = ct * 16 + lrow;
        float bsv = bs[c], bpv = bp[c];
        #pragma unroll
        for (int r = 0; r < 4; ++r) {
            if (gn[r] < N_NODES)
                out[(size_t)gn[r] * F + c] = accS[ct][r] + bsv + (accP[ct][r] + ms[r] * bpv) * inv[r];
        }
    }
}

static inline char* align16(char* p) {
    return (char*)(((uintptr_t)p + 15) & ~(uintptr_t)15);
}

extern "C" void kernel_launch(void* const* d_in, const int* in_sizes, int n_in,
                              void* d_out, int out_size, void* d_ws, size_t ws_size,
                              hipStream_t stream) {
    const float* feat  = (const float*)d_in[0];
    const float* efeat = (const float*)d_in[1];
    const int*   src   = (const int*)d_in[2];
    const int*   dst   = (const int*)d_in[3];
    const float* Wp    = (const float*)d_in[4];
    const float* bp    = (const float*)d_in[5];
    const float* Ws    = (const float*)d_in[6];
    const float* bs    = (const float*)d_in[7];
    float* out = (float*)d_out;

    // workspace layout
    char* p = (char*)d_ws;
    unsigned* histW    = (unsigned*)p; p += (size_t)NB_E * NPAIR * 4;       // 12.8 MB u16[NB_E][N_NODES] as u32 pairs
    unsigned* baseW    = (unsigned*)p; p += (size_t)NB_E * NPAIR * 4;       // 12.8 MB
    unsigned short* rank16 = (unsigned short*)p; p += (size_t)N_EDGES * 2;  // 1.6 MB
    int*      syncCnt  = (int*)p;      p += 16;
    int*      offsets  = (int*)p;      p += (size_t)(N_NODES + 1) * 4;      p = align16(p);
    int*      blockSums= (int*)p;      p += (size_t)SCAN_BLK * 4;           p = align16(p);
    unsigned* csr      = (unsigned*)p; p += (size_t)N_EDGES * 4;            p = align16(p);
    float*    msum     = (float*)p;    p += (size_t)N_NODES * 4;            p = align16(p);
    _Float16* featH    = (_Float16*)p; p += (size_t)(N_NODES + PAD_ROWS) * F * 2; p = align16(p);
    _Float16* aggH     = (_Float16*)p; p += (size_t)(N_NODES + PAD_ROWS) * F * 2; p = align16(p);
    _Float16* WsH      = (_Float16*)p; p += (size_t)F * F * 2;              p = align16(p);
    _Float16* WpH      = (_Float16*)p;

    k_prep<<<(N_NODES * F / 8 + 255) / 256, 256, 0, stream>>>(feat, Wp, Ws, featH, WpH, WsH);
    k_hist<<<NB_E, 1024, 0, stream>>>(dst, histW, rank16, syncCnt);
    k_scan<<<SCAN_NB, SCAN_BLK, 0, stream>>>(histW, baseW, blockSums, offsets, syncCnt);
    k_fill<<<(N_EDGES + 255) / 256, 256, 0, stream>>>(src, dst, efeat, offsets, (const unsigned short*)baseW, rank16, csr);
    k_gather<<<(N_NODES * 64 + 255) / 256, 256, 0, stream>>>(offsets, csr, featH, msum, aggH);
    fused_gemm<<<(N_NODES + 127) / 128, 512, 0, stream>>>(featH, aggH, WpH, bp, WsH, bs, msum, offsets, out);
}

// Round 5
// 185.591 us; speedup vs baseline: 1.0331x; 1.0331x over previous
//
#include <hip/hip_runtime.h>
#include <hip/hip_bf16.h>

#define N_NODES 50000
#define N_EDGES 800000
#define F 128
#define PAD_ROWS 64   // tail-tile slack for fused_gemm A-loads
#define SCAN_BLK 256
#define NPAIR (N_NODES / 2)                      // 25000 packed node-pairs
#define SCAN_NB ((NPAIR + SCAN_BLK - 1) / SCAN_BLK)   // 98
#define NB_E 128                                 // edge blocks for counting sort
#define E_PER (N_EDGES / NB_E)                   // 6250
#define FRONT_THR (NB_E * 1024)                  // 131072 threads in k_front grid

typedef _Float16 half8 __attribute__((ext_vector_type(8)));
typedef float floatx4 __attribute__((ext_vector_type(4)));

__device__ inline float wave_sum(float v) {
    #pragma unroll
    for (int o = 32; o > 0; o >>= 1) v += __shfl_xor(v, o);
    return v;
}

// high 16 bits hold an fp16 payload
__device__ inline float hi16_of(unsigned u) {
    union { unsigned short s; _Float16 h; } c;
    c.s = (unsigned short)(u >> 16);
    return (float)c.h;
}

__device__ inline half8 cvt8(const float4* p) {
    float4 a = p[0], b = p[1];
    half8 h;
    h[0]=(_Float16)a.x; h[1]=(_Float16)a.y; h[2]=(_Float16)a.z; h[3]=(_Float16)a.w;
    h[4]=(_Float16)b.x; h[5]=(_Float16)b.y; h[6]=(_Float16)b.z; h[7]=(_Float16)b.w;
    return h;
}

// ---------------- k_front: fused prep (fp32->fp16 streaming) + per-block LDS histogram + rank ----------------
// 100 KB static LDS, 128 blocks x 1024 threads. Hist is LDS-atomic-bound, prep is
// VMEM-streaming-bound: placing the feat-conversion loop between the hist-atomic loop
// and the final barrier lets waves overlap the two pipes inside one dispatch.
// Counts per block per node <= 6250 < 2^16, so packed-pair atomicAdd(1 << 16*(d&1))
// never carries across halves. The atomic's return value IS the edge's within-block
// rank -> persist to rank16 so k_fill needs no LDS at all.
__global__ __launch_bounds__(1024) void k_front(const float* __restrict__ feat,
                                                const float* __restrict__ Wp,
                                                const float* __restrict__ Ws,
                                                const int* __restrict__ dst,
                                                _Float16* __restrict__ featH,
                                                _Float16* __restrict__ WpH,
                                                _Float16* __restrict__ WsH,
                                                unsigned* __restrict__ histW,
                                                unsigned short* __restrict__ rank16,
                                                int* __restrict__ syncCnt) {
    __shared__ unsigned cnt[NPAIR];   // 100 KB
    int t = threadIdx.x;
    int g = blockIdx.x * 1024 + t;
    for (int i = t; i < NPAIR; i += 1024) cnt[i] = 0;
    if (blockIdx.x == 0 && t == 0) *syncCnt = 0;   // reset for k_scan (ordered by kernel boundary)
    __syncthreads();

    // ---- edge histogram + rank (LDS atomics) ----
    int base = blockIdx.x * E_PER;
    for (int i = t; i < E_PER; i += 1024) {
        int d = dst[base + i];
        int sh = (d & 1) * 16;
        unsigned old = atomicAdd(&cnt[d >> 1], 1u << sh);
        rank16[base + i] = (unsigned short)((old >> sh) & 0xFFFFu);
    }

    // ---- feat conversion (independent streaming; overlaps other waves' atomics) ----
    for (int i = g; i < N_NODES * F / 8; i += FRONT_THR) {
        ((half8*)featH)[i] = cvt8((const float4*)feat + (size_t)i * 2);
    }
    // ---- weights (tiny) ----
    for (int i = g; i < F * F / 8; i += FRONT_THR) {
        ((half8*)WpH)[i] = cvt8((const float4*)Wp + (size_t)i * 2);
        ((half8*)WsH)[i] = cvt8((const float4*)Ws + (size_t)i * 2);
    }

    __syncthreads();
    unsigned* out = histW + (size_t)blockIdx.x * NPAIR;
    for (int i = t; i < NPAIR; i += 1024) out[i] = cnt[i];
}

// ---------------- k_scan: per-node prefix over NB_E hist rows -> base16 + offsets (fused spin-sync) ----------------
// 98 blocks x 256 threads (one thread per node PAIR): trivially co-resident, spin cannot deadlock.
__global__ __launch_bounds__(SCAN_BLK) void k_scan(const unsigned* __restrict__ histW,
                                                   unsigned* __restrict__ baseW,
                                                   int* __restrict__ blockSums,
                                                   int* __restrict__ offsets,
                                                   int* __restrict__ syncCnt) {
    __shared__ int s[SCAN_BLK];
    __shared__ int bs[SCAN_BLK];
    int t = threadIdx.x;
    int i = blockIdx.x * SCAN_BLK + t;   // pair index: nodes 2i, 2i+1

    // serial prefix over edge-blocks; separate lo/hi running sums (u16 halves)
    int dLo = 0, dHi = 0;
    if (i < NPAIR) {
        #pragma unroll 8
        for (int b = 0; b < NB_E; ++b) {
            unsigned w = histW[(size_t)b * NPAIR + i];
            baseW[(size_t)b * NPAIR + i] = (unsigned)dLo | ((unsigned)dHi << 16);
            dLo += (int)(w & 0xFFFFu);
            dHi += (int)(w >> 16);
        }
    }
    int dT = dLo + dHi;

    // in-block inclusive scan of pair totals
    s[t] = dT;
    __syncthreads();
    for (int o = 1; o < SCAN_BLK; o <<= 1) {
        int u = (t >= o) ? s[t - o] : 0;
        __syncthreads();
        s[t] += u;
        __syncthreads();
    }
    int incl = s[t];
    int total = s[SCAN_BLK - 1];

    // publish block total, device-scope counter barrier
    if (t == 0) {
        __hip_atomic_store(&blockSums[blockIdx.x], total, __ATOMIC_RELAXED, __HIP_MEMORY_SCOPE_AGENT);
        __hip_atomic_fetch_add(syncCnt, 1, __ATOMIC_RELEASE, __HIP_MEMORY_SCOPE_AGENT);
        while (__hip_atomic_load(syncCnt, __ATOMIC_ACQUIRE, __HIP_MEMORY_SCOPE_AGENT) < SCAN_NB) {
            __builtin_amdgcn_s_sleep(1);
        }
    }
    __syncthreads();

    // redundant top-level scan of the 98 block sums
    int v = (t < SCAN_NB) ? __hip_atomic_load(&blockSums[t], __ATOMIC_RELAXED, __HIP_MEMORY_SCOPE_AGENT) : 0;
    bs[t] = v;
    __syncthreads();
    for (int o = 1; o < SCAN_BLK; o <<= 1) {
        int u = (t >= o) ? bs[t - o] : 0;
        __syncthreads();
        bs[t] += u;
        __syncthreads();
    }
    int blockPrefix = (blockIdx.x == 0) ? 0 : bs[blockIdx.x - 1];
    if (i < NPAIR) {
        int excl = incl - dT + blockPrefix;
        offsets[2 * i]     = excl;
        offsets[2 * i + 1] = excl + dLo;
    }
    if (blockIdx.x == 0 && t == 0) offsets[N_NODES] = N_EDGES;
}

// ---------------- k_fill: pure streaming scatter (no LDS, full occupancy) ----------------
// pos = offsets[d] + base16[b][d] + rank16[e]; all per-edge inputs coalesced,
// two random 2-4 B loads per edge hidden by massive TLP (3125 blocks).
__global__ __launch_bounds__(256) void k_fill(const int* __restrict__ src,
                                              const int* __restrict__ dst,
                                              const float* __restrict__ efeat,
                                              const int* __restrict__ offsets,
                                              const unsigned short* __restrict__ base16,
                                              const unsigned short* __restrict__ rank16,
                                              unsigned* __restrict__ csr) {
    int e = blockIdx.x * 256 + threadIdx.x;
    if (e < N_EDGES) {
        int d = dst[e];
        int b = e / E_PER;
        union { _Float16 h; unsigned short s; } c;
        c.h = (_Float16)efeat[e];
        int pos = offsets[d] + (int)base16[(size_t)b * N_NODES + d] + (int)rank16[e];
        csr[pos] = (unsigned)src[e] | ((unsigned)c.s << 16);
    }
}

// ---------------- k_gather: one wave per node; single-sweep fast path for deg<=64 ----------------
__global__ __launch_bounds__(256) void k_gather(const int* __restrict__ offsets,
                                                const unsigned* __restrict__ csr,
                                                const _Float16* __restrict__ featH,
                                                float* __restrict__ msum,
                                                _Float16* __restrict__ aggH) {
    int wid  = (blockIdx.x * 256 + threadIdx.x) >> 6;   // node id
    int lane = threadIdx.x & 63;
    if (wid >= N_NODES) return;
    int beg = offsets[wid], end = offsets[wid + 1];
    int deg = end - beg;
    int grp = lane >> 4;        // 0..3
    int lig = lane & 15;        // lane in group

    float acc[8];
    #pragma unroll
    for (int k = 0; k < 8; ++k) acc[k] = 0.f;
    float msacc = 0.f;

    if (deg <= 64) {
        // FAST PATH (covers essentially all nodes; avg deg = 16):
        // one csr read, one exp per edge (owner lane), shfl both src and m.
        int j = beg + lane;
        bool live = j < end;
        unsigned u = live ? csr[j] : 0u;
        float w = live ? hi16_of(u) : 0.f;
        float ws = wave_sum(w);
        float inv = (deg > 0) ? (1.0f / ws) : 0.0f;
        float mv = live ? __expf(-w * inv) : 0.f;
        msacc = mv;

        for (int it = 0; it < deg; it += 8) {
            int idx1 = it + grp;
            int idx2 = it + 4 + grp;
            unsigned u1 = __shfl(u, idx1);
            unsigned u2 = __shfl(u, idx2);
            float m1 = __shfl(mv, idx1);
            float m2 = __shfl(mv, idx2);
            bool p1 = idx1 < deg, p2 = idx2 < deg;
            half8 v1, v2;
            if (p1) v1 = *(const half8*)(featH + (size_t)(u1 & 0xFFFFu) * F + lig * 8);
            if (p2) v2 = *(const half8*)(featH + (size_t)(u2 & 0xFFFFu) * F + lig * 8);
            if (p1) {
                #pragma unroll
                for (int k = 0; k < 8; ++k) acc[k] += m1 * (float)v1[k];
            }
            if (p2) {
                #pragma unroll
                for (int k = 0; k < 8; ++k) acc[k] += m2 * (float)v2[k];
            }
        }
    } else {
        // SLOW PATH: two-pass (wsum sweep then main), exp once per edge + shfl
        float wsum = 0.f;
        for (int c = beg; c < end; c += 64) {
            int j = c + lane;
            wsum += (j < end) ? hi16_of(csr[j]) : 0.f;
        }
        wsum = wave_sum(wsum);
        float inv = 1.0f / wsum;

        for (int c = beg; c < end; c += 64) {
            int j = c + lane;
            int cnt = end - c; if (cnt > 64) cnt = 64;
            bool live = j < end;
            unsigned u = live ? csr[j] : 0u;
            float mv = live ? __expf(-hi16_of(u) * inv) : 0.f;
            msacc += mv;
            for (int it = 0; it < cnt; it += 8) {
                int idx1 = it + grp;
                int idx2 = it + 4 + grp;
                unsigned u1 = __shfl(u, idx1);
                unsigned u2 = __shfl(u, idx2);
                float m1 = __shfl(mv, idx1);
                float m2 = __shfl(mv, idx2);
                bool p1 = idx1 < cnt, p2 = idx2 < cnt;
                half8 v1, v2;
                if (p1) v1 = *(const half8*)(featH + (size_t)(u1 & 0xFFFFu) * F + lig * 8);
                if (p2) v2 = *(const half8*)(featH + (size_t)(u2 & 0xFFFFu) * F + lig * 8);
                if (p1) {
                    #pragma unroll
                    for (int k = 0; k < 8; ++k) acc[k] += m1 * (float)v1[k];
                }
                if (p2) {
                    #pragma unroll
                    for (int k = 0; k < 8; ++k) acc[k] += m2 * (float)v2[k];
                }
            }
        }
    }

    #pragma unroll
    for (int k = 0; k < 8; ++k) {
        acc[k] += __shfl_xor(acc[k], 16);
        acc[k] += __shfl_xor(acc[k], 32);
    }
    msacc = wave_sum(msacc);

    if (grp == 0) {
        half8 o;
        #pragma unroll
        for (int k = 0; k < 8; ++k) o[k] = (_Float16)acc[k];
        ((half8*)(aggH + (size_t)wid * F))[lig] = o;
    }
    if (lane == 0) msum[wid] = msacc;
}

// ---------------- fused_gemm: dual MFMA GEMM, weights staged in LDS ----------------
__global__ __launch_bounds__(512, 4) void fused_gemm(const _Float16* __restrict__ featH,
                                                     const _Float16* __restrict__ aggH,
                                                     const _Float16* __restrict__ WpH,
                                                     const float* __restrict__ bp,
                                                     const _Float16* __restrict__ WsH,
                                                     const float* __restrict__ bs,
                                                     const float* __restrict__ msum,
                                                     const int* __restrict__ offsets,
                                                     float* __restrict__ out) {
    __shared__ half8 sBS[2048];   // 32 KB
    __shared__ half8 sBP[2048];   // 32 KB

    int t = threadIdx.x;
    for (int c = t; c < 2048; c += 512) {
        int o  = c >> 4;
        int k8 = c & 15;
        int lane = (o & 15) | ((k8 & 3) << 4);
        int slot = ((o >> 4) * 4 + (k8 >> 2)) * 64 + lane;
        sBS[slot] = ((const half8*)WsH)[c];
        sBP[slot] = ((const half8*)WpH)[c];
    }
    __syncthreads();

    int wv   = t >> 6;
    int lane = t & 63;
    int n0   = blockIdx.x * 128 + wv * 16;   // tail waves compute garbage on pad rows; stores guarded
    int lrow = lane & 15;
    int quad = lane >> 4;

    floatx4 accS[8], accP[8];
    #pragma unroll
    for (int c = 0; c < 8; ++c) {
        accS[c] = (floatx4){0.f, 0.f, 0.f, 0.f};
        accP[c] = (floatx4){0.f, 0.f, 0.f, 0.f};
    }

    const half8* fr = (const half8*)(featH + (size_t)(n0 + lrow) * F) + quad;
    const half8* ar = (const half8*)(aggH  + (size_t)(n0 + lrow) * F) + quad;

    #pragma unroll
    for (int kt = 0; kt < 4; ++kt) {
        half8 aF = fr[kt * 4];
        half8 aA = ar[kt * 4];
        #pragma unroll
        for (int ct = 0; ct < 8; ++ct) {
            half8 bS = sBS[(ct * 4 + kt) * 64 + lane];
            half8 bP = sBP[(ct * 4 + kt) * 64 + lane];
            accS[ct] = __builtin_amdgcn_mfma_f32_16x16x32_f16(aF, bS, accS[ct], 0, 0, 0);
            accP[ct] = __builtin_amdgcn_mfma_f32_16x16x32_f16(aA, bP, accP[ct], 0, 0, 0);
        }
    }

    float ms[4], inv[4];
    int gn[4];
    #pragma unroll
    for (int r = 0; r < 4; ++r) {
        int g = n0 + quad * 4 + r;
        gn[r] = g;
        bool ok = g < N_NODES;
        ms[r]  = ok ? msum[g] : 0.f;
        float dv = ok ? fmaxf((float)(offsets[g + 1] - offsets[g]), 1.0f) : 1.0f;
        inv[r] = 1.0f / dv;
    }
    #pragma unroll
    for (int ct = 0; ct < 8; ++ct) {
        int c = ct * 16 + lrow;
        float bsv = bs[c], bpv = bp[c];
        #pragma unroll
        for (int r = 0; r < 4; ++r) {
            if (gn[r] < N_NODES)
                out[(size_t)gn[r] * F + c] = accS[ct][r] + bsv + (accP[ct][r] + ms[r] * bpv) * inv[r];
        }
    }
}

static inline char* align16(char* p) {
    return (char*)(((uintptr_t)p + 15) & ~(uintptr_t)15);
}

extern "C" void kernel_launch(void* const* d_in, const int* in_sizes, int n_in,
                              void* d_out, int out_size, void* d_ws, size_t ws_size,
                              hipStream_t stream) {
    const float* feat  = (const float*)d_in[0];
    const float* efeat = (const float*)d_in[1];
    const int*   src   = (const int*)d_in[2];
    const int*   dst   = (const int*)d_in[3];
    const float* Wp    = (const float*)d_in[4];
    const float* bp    = (const float*)d_in[5];
    const float* Ws    = (const float*)d_in[6];
    const float* bs    = (const float*)d_in[7];
    float* out = (float*)d_out;

    // workspace layout
    char* p = (char*)d_ws;
    unsigned* histW    = (unsigned*)p; p += (size_t)NB_E * NPAIR * 4;       // 12.8 MB u16[NB_E][N_NODES] as u32 pairs
    unsigned* baseW    = (unsigned*)p; p += (size_t)NB_E * NPAIR * 4;       // 12.8 MB
    unsigned short* rank16 = (unsigned short*)p; p += (size_t)N_EDGES * 2;  // 1.6 MB
    int*      syncCnt  = (int*)p;      p += 16;
    int*      offsets  = (int*)p;      p += (size_t)(N_NODES + 1) * 4;      p = align16(p);
    int*      blockSums= (int*)p;      p += (size_t)SCAN_BLK * 4;           p = align16(p);
    unsigned* csr      = (unsigned*)p; p += (size_t)N_EDGES * 4;            p = align16(p);
    float*    msum     = (float*)p;    p += (size_t)N_NODES * 4;            p = align16(p);
    _Float16* featH    = (_Float16*)p; p += (size_t)(N_NODES + PAD_ROWS) * F * 2; p = align16(p);
    _Float16* aggH     = (_Float16*)p; p += (size_t)(N_NODES + PAD_ROWS) * F * 2; p = align16(p);
    _Float16* WsH      = (_Float16*)p; p += (size_t)F * F * 2;              p = align16(p);
    _Float16* WpH      = (_Float16*)p;

    k_front<<<NB_E, 1024, 0, stream>>>(feat, Wp, Ws, dst, featH, WpH, WsH, histW, rank16, syncCnt);
    k_scan<<<SCAN_NB, SCAN_BLK, 0, stream>>>(histW, baseW, blockSums, offsets, syncCnt);
    k_fill<<<(N_EDGES + 255) / 256, 256, 0, stream>>>(src, dst, efeat, offsets, (const unsigned short*)baseW, rank16, csr);
    k_gather<<<(N_NODES * 64 + 255) / 256, 256, 0, stream>>>(offsets, csr, featH, msum, aggH);
    fused_gemm<<<(N_NODES + 127) / 128, 512, 0, stream>>>(featH, aggH, WpH, bp, WsH, bs, msum, offsets, out);
}